// Round 23
// baseline (70.413 us; speedup 1.0000x reference)
//
#include <hip/hip_runtime.h>
#include <math.h>

#define NQ 10
#define DIM 1024
#define HID 64
#define NT 256

template<int CTRL>
__device__ __forceinline__ float fdpp(float v) {
    return __int_as_float(__builtin_amdgcn_update_dpp(
        0, __float_as_int(v), CTRL, 0xF, 0xF, true));
}

// fused RY*RX 2x2 complex gate (validated r2..r22)
__device__ __forceinline__ void l1pair(float4 g, float& r0, float& i0, float& r1, float& i1) {
    float n0r = g.x * r0 - g.y * i0 - g.z * r1 + g.w * i1;
    float n0i = g.x * i0 + g.y * r0 - g.z * i1 - g.w * r1;
    float n1r = g.z * r0 + g.w * i0 + g.x * r1 + g.y * i1;
    float n1i = g.z * i0 - g.w * r0 + g.x * i1 - g.y * r1;
    r0 = n0r; i0 = n0i; r1 = n1r; i1 = n1i;
}
__device__ __forceinline__ void l2pair(float2 g, float& r0, float& i0, float& r1, float& i1) {
    float n0r = g.x * r0 - g.y * r1, n0i = g.x * i0 - g.y * i1;
    float n1r = g.y * r0 + g.x * r1, n1i = g.y * i0 + g.x * i1;
    r0 = n0r; i0 = n0i; r1 = n1r; i1 = n1i;
}

// cross-lane fetch from lane^(1<<P): DPP for P=0,1, shfl for P>=2 (validated)
template<int P>
__device__ __forceinline__ float xl(float v) {
    if constexpr (P == 0)      return fdpp<0xB1>(v);
    else if constexpr (P == 1) return fdpp<0x4E>(v);
    else                       return __shfl_xor(v, 1 << P, 64);
}

template<int P>
__device__ __forceinline__ void gate4_l1(float4 g, int tid, float (&vr)[4], float (&vi)[4]) {
    const float fsb = ((tid >> P) & 1) ? 1.f : -1.f;
    const float Bs = fsb * g.y, Cs = fsb * g.z;
    #pragma unroll
    for (int m = 0; m < 4; m++) {
        float ur = xl<P>(vr[m]);
        float ui = xl<P>(vi[m]);
        float nr = g.x * vr[m] + Bs * vi[m] + Cs * ur + g.w * ui;
        float ni = g.x * vi[m] - Bs * vr[m] + Cs * ui - g.w * ur;
        vr[m] = nr; vi[m] = ni;
    }
}
template<int P>
__device__ __forceinline__ void gate4_l2(float2 g, int tid, float (&vr)[4], float (&vi)[4]) {
    const float fsb = ((tid >> P) & 1) ? 1.f : -1.f;
    const float ssf = fsb * g.y;
    #pragma unroll
    for (int m = 0; m < 4; m++) {
        float ur = xl<P>(vr[m]);
        float ui = xl<P>(vi[m]);
        vr[m] = g.x * vr[m] + ssf * ur;
        vi[m] = g.x * vi[m] + ssf * ui;
    }
}

// ---- dual-row obs partials, 2-pass (r18 algebra x r13 dual x r19 pass-split,
// all validated). Interleaved layout: element d at byte 16d = (re0,im0,re1,im1).
// PASS covers r in [8*PASS, 8*PASS+8), j = r - 8*PASS.
template<int PASS, int HB, int CM>
__device__ __forceinline__ float2 obs_halved_p2(
        const float (&a0r)[8], const float (&a0i)[8],
        const float (&a1r)[8], const float (&a1i)[8],
        const char* stb, int base_cx, int w1) {
    float p0 = 0.f, p1 = 0.f;
    if constexpr (HB == 3) {                 // kept set (bit3=0) lives in pass 0
        if constexpr (PASS == 1) return make_float2(0.f, 0.f);
        #pragma unroll
        for (int j = 0; j < 8; j++) {
            const float4 c = *(const float4*)(stb + (base_cx ^ (j << 10)));
            float t0, t1;
            if constexpr (CM) { t0 = a0r[j] * c.y - a0i[j] * c.x;
                                t1 = a1r[j] * c.w - a1i[j] * c.z; }
            else              { t0 = a0r[j] * c.x + a0i[j] * c.y;
                                t1 = a1r[j] * c.z + a1i[j] * c.w; }
            const float cf = __int_as_float(0x40000000 | (((w1 >> j) & 1) << 31));
            p0 = fmaf(cf, t0, p0); p1 = fmaf(cf, t1, p1);
        }
    } else {
        #pragma unroll
        for (int ii = 0; ii < 4; ii++) {
            const int idx = PASS * 4 + ii;   // r(idx) monotone: idx<4 <=> r<8 (r19)
            const int r   = ((idx >> HB) << (HB + 1)) | (idx & ((1 << HB) - 1));
            const int j   = r - PASS * 8;
            const float4 c = *(const float4*)(stb + (base_cx ^ (r << 10)));
            float t0, t1;
            if constexpr (CM) { t0 = a0r[j] * c.y - a0i[j] * c.x;
                                t1 = a1r[j] * c.w - a1i[j] * c.z; }
            else              { t0 = a0r[j] * c.x + a0i[j] * c.y;
                                t1 = a1r[j] * c.z + a1i[j] * c.w; }
            const float cf = __int_as_float(0x40000000 | (((w1 >> r) & 1) << 31));
            p0 = fmaf(cf, t0, p0); p1 = fmaf(cf, t1, p1);
        }
    }
    return make_float2(p0, p1);
}
template<int PASS, int CM>
__device__ __forceinline__ float2 obs_full_p2(
        const float (&a0r)[8], const float (&a0i)[8],
        const float (&a1r)[8], const float (&a1i)[8],
        const char* stb, int base_c, int w1) {
    float p0 = 0.f, p1 = 0.f;
    #pragma unroll
    for (int j = 0; j < 8; j++) {
        const int r = PASS * 8 + j;
        const float4 c = *(const float4*)(stb + (base_c ^ (r << 10)));
        float t0, t1;
        if constexpr (CM) { t0 = a0r[j] * c.y - a0i[j] * c.x;
                            t1 = a1r[j] * c.w - a1i[j] * c.z; }
        else              { t0 = a0r[j] * c.x + a0i[j] * c.y;
                            t1 = a1r[j] * c.z + a1i[j] * c.w; }
        const float cf = __int_as_float(0x3F800000 | (((w1 >> r) & 1) << 31));
        p0 = fmaf(cf, t0, p0); p1 = fmaf(cf, t1, p1);
    }
    return make_float2(p0, p1);
}
template<int PASS>
__device__ __forceinline__ float2 obs_diag_p2(
        const float (&a0r)[8], const float (&a0i)[8],
        const float (&a1r)[8], const float (&a1i)[8], int w1) {
    float p0 = 0.f, p1 = 0.f;
    #pragma unroll
    for (int j = 0; j < 8; j++) {
        const int r = PASS * 8 + j;
        float t0 = fmaf(a0r[j], a0r[j], a0i[j] * a0i[j]);
        float t1 = fmaf(a1r[j], a1r[j], a1i[j] * a1i[j]);
        const float cf = __int_as_float(0x3F800000 | (((w1 >> r) & 1) << 31));
        p0 = fmaf(cf, t0, p0); p1 = fmaf(cf, t1, p1);
    }
    return make_float2(p0, p1);
}
__device__ __forceinline__ int4 make_meta(const int* op_codes, int o) {
    int xm = 0, yzm = 0, ny = 0;
    #pragma unroll
    for (int q = 0; q < NQ; q++) {
        int code = op_codes[o * NQ + q];
        int bit  = 1 << (NQ - 1 - q);       // qubit q = element bit 9-q
        if (code == 1) xm |= bit;
        else if (code == 2) { xm |= bit; yzm |= bit; ny++; }
        else if (code == 3) yzm |= bit;
    }
    const int cm = ny & 1, gflip = (ny >> 1) & 1;
    const int yh = yzm >> 6;
    int w1 = 0;
    #pragma unroll
    for (int r = 0; r < 16; r++)
        w1 |= ((__popc(r & yh) & 1) ^ gflip) << r;
    const int xmr = (xm >> 6) & 15;
    int hbc;
    if (xm == 0)      hbc = 5;              // diagonal
    else if (xmr)     hbc = __ffs(xmr) - 1; // halved on reg bit 0..3
    else              hbc = 4;              // lane-only xm: full 16
    return make_int4(xm, yzm & 63, w1, hbc | (cm << 3));
}
template<int PASS>
__device__ __forceinline__ float2 obs_one_p2(int4 mt, int lane,
        const float (&a0r)[8], const float (&a0i)[8],
        const float (&a1r)[8], const float (&a1i)[8], const char* stb) {
    const int xm   = __builtin_amdgcn_readfirstlane(mt.x);
    const int yzml = __builtin_amdgcn_readfirstlane(mt.y);
    const int w1   = __builtin_amdgcn_readfirstlane(mt.z);
    const int knd  = __builtin_amdgcn_readfirstlane(mt.w);
    const int hbc = knd & 7, cm = knd >> 3;
    float2 p;
    if (hbc == 5) {
        p = obs_diag_p2<PASS>(a0r, a0i, a1r, a1i, w1);
    } else {
        const int xml = xm & 63, xmr = (xm >> 6) & 15;
        const int base_cx = (xmr << 10) | ((lane ^ xml) << 4);
        switch (hbc | (cm << 3)) {
            case 0:     p = obs_halved_p2<PASS,0,0>(a0r,a0i,a1r,a1i, stb, base_cx, w1); break;
            case 1:     p = obs_halved_p2<PASS,1,0>(a0r,a0i,a1r,a1i, stb, base_cx, w1); break;
            case 2:     p = obs_halved_p2<PASS,2,0>(a0r,a0i,a1r,a1i, stb, base_cx, w1); break;
            case 3:     p = obs_halved_p2<PASS,3,0>(a0r,a0i,a1r,a1i, stb, base_cx, w1); break;
            case 4:     p = obs_full_p2<PASS,0>(a0r,a0i,a1r,a1i, stb, base_cx, w1);     break;
            case 8 | 0: p = obs_halved_p2<PASS,0,1>(a0r,a0i,a1r,a1i, stb, base_cx, w1); break;
            case 8 | 1: p = obs_halved_p2<PASS,1,1>(a0r,a0i,a1r,a1i, stb, base_cx, w1); break;
            case 8 | 2: p = obs_halved_p2<PASS,2,1>(a0r,a0i,a1r,a1i, stb, base_cx, w1); break;
            case 8 | 3: p = obs_halved_p2<PASS,3,1>(a0r,a0i,a1r,a1i, stb, base_cx, w1); break;
            default:    p = obs_full_p2<PASS,1>(a0r,a0i,a1r,a1i, stb, base_cx, w1);     break;
        }
    }
    const int slb = (__popc(lane & yzml) & 1) << 31;
    p.x = __int_as_float(__float_as_int(p.x) ^ slb);
    p.y = __int_as_float(__float_as_int(p.y) ^ slb);
    return p;
}

// 2 rows per 256-thread block, element-interleaved LDS state (re0,im0,re1,im1).
// Gates run validated scalar routines on two register sets; every DS access is
// one b128 serving both rows (DS instrs/row halved, decode/row halved,
// barriers/row halved). Obs: 2 chunks x 2 passes (32 a-side regs per pass),
// chunk-8 transpose drain. LDS ~36KB -> 4 blocks/CU, grid 1024 = one batch.
__global__ __launch_bounds__(NT, 4) void qsa_kernel(
    const float* __restrict__ x,
    const float* __restrict__ rx0,
    const float* __restrict__ ry0,
    const float* __restrict__ ry1,
    const int*   __restrict__ op_codes,
    float* __restrict__ out)
{
    __shared__ float4 st4[DIM];             // interleaved state (16 KB)
    __shared__ float2 cb[4][64 * 9];        // chunk-8 transpose buffers (18 KB)
    __shared__ float4 s_l1[NQ];
    __shared__ float2 s_l2[NQ];
    __shared__ int4   s_meta[HID];
    __shared__ float2 wsum[4];

    const int tid  = threadIdx.x;
    const int lane = tid & 63;
    const int wave = tid >> 6;
    const int row0 = blockIdx.x * 2;        // grid = 1024
    const int row1 = row0 + 1;

    // ---- setup (validated) ----
    if (tid < NQ) {
        float a = 0.5f * rx0[tid], b = 0.5f * ry0[tid];
        float c1 = cosf(a), s1 = sinf(a), c2 = cosf(b), s2 = sinf(b);
        s_l1[tid] = make_float4(c1 * c2, s1 * s2, s2 * c1, c2 * s1);  // A,B,C,D
    } else if (tid < 2 * NQ) {
        float a = 0.5f * ry1[tid - NQ];
        s_l2[tid - NQ] = make_float2(cosf(a), sinf(a));
    }
    if (tid >= 64 && tid < 64 + HID)
        s_meta[tid - 64] = make_meta(op_codes, tid - 64);

    // ---- load both rows + normalize (independent reductions) ----
    float vrx[4], vix[4], vry[4], viy[4];
    {
        const float* xp = x + (size_t)row0 * DIM;
        float s0 = 0.f, s1 = 0.f;
        #pragma unroll
        for (int m = 0; m < 4; m++) {
            vrx[m] = xp[tid + NT * m];
            vry[m] = xp[DIM + tid + NT * m];
            vix[m] = 0.f; viy[m] = 0.f;
            s0 += vrx[m] * vrx[m];
            s1 += vry[m] * vry[m];
        }
        #pragma unroll
        for (int off = 32; off; off >>= 1) {
            s0 += __shfl_xor(s0, off, 64);
            s1 += __shfl_xor(s1, off, 64);
        }
        if (lane == 0) wsum[wave] = make_float2(s0, s1);
    }
    __syncthreads();                                     // B0 (fences tables too)
    {
        float t0 = wsum[0].x + wsum[1].x + wsum[2].x + wsum[3].x;
        float t1 = wsum[0].y + wsum[1].y + wsum[2].y + wsum[3].y;
        float inv0 = 1.0f / sqrtf(t0);
        float inv1 = 1.0f / sqrtf(t1);
        #pragma unroll
        for (int m = 0; m < 4; m++) { vrx[m] *= inv0; vry[m] *= inv1; }
    }

    // ---- layer 1 (r22 schedule): bits 9,8 in-reg; bits 5..0 shfl/DPP ----
    {
        float4 g0 = s_l1[0];
        l1pair(g0, vrx[0], vix[0], vrx[2], vix[2]);
        l1pair(g0, vrx[1], vix[1], vrx[3], vix[3]);
        l1pair(g0, vry[0], viy[0], vry[2], viy[2]);
        l1pair(g0, vry[1], viy[1], vry[3], viy[3]);
        float4 g1 = s_l1[1];
        l1pair(g1, vrx[0], vix[0], vrx[1], vix[1]);
        l1pair(g1, vrx[2], vix[2], vrx[3], vix[3]);
        l1pair(g1, vry[0], viy[0], vry[1], viy[1]);
        l1pair(g1, vry[2], viy[2], vry[3], viy[3]);
    }
    gate4_l1<5>(s_l1[4], tid, vrx, vix); gate4_l1<5>(s_l1[4], tid, vry, viy);
    gate4_l1<4>(s_l1[5], tid, vrx, vix); gate4_l1<4>(s_l1[5], tid, vry, viy);
    gate4_l1<3>(s_l1[6], tid, vrx, vix); gate4_l1<3>(s_l1[6], tid, vry, viy);
    gate4_l1<2>(s_l1[7], tid, vrx, vix); gate4_l1<2>(s_l1[7], tid, vry, viy);
    gate4_l1<1>(s_l1[8], tid, vrx, vix); gate4_l1<1>(s_l1[8], tid, vry, viy);
    gate4_l1<0>(s_l1[9], tid, vrx, vix); gate4_l1<0>(s_l1[9], tid, vry, viy);
    #pragma unroll
    for (int m = 0; m < 4; m++)
        st4[tid + NT * m] = make_float4(vrx[m], vix[m], vry[m], viy[m]);
    __syncthreads();                                     // B1
    {   // l1 bits 7,6: 4x4 in place (both rows) -> complete post-l1 image
        int base = lane | (wave << 8);
        float4 w00 = st4[base], w01 = st4[base | 64], w10 = st4[base | 128], w11 = st4[base | 192];
        float4 g2 = s_l1[2], g3 = s_l1[3];
        l1pair(g2, w00.x, w00.y, w10.x, w10.y);
        l1pair(g2, w00.z, w00.w, w10.z, w10.w);
        l1pair(g2, w01.x, w01.y, w11.x, w11.y);
        l1pair(g2, w01.z, w01.w, w11.z, w11.w);
        l1pair(g3, w00.x, w00.y, w01.x, w01.y);
        l1pair(g3, w00.z, w00.w, w01.z, w01.w);
        l1pair(g3, w10.x, w10.y, w11.x, w11.y);
        l1pair(g3, w10.z, w10.w, w11.z, w11.w);
        st4[base] = w00; st4[base | 64] = w01; st4[base | 128] = w10; st4[base | 192] = w11;
    }
    __syncthreads();                                     // B2: post-l1 ready

    // ---- CNOT ring: gather both rows from post-l1 image ----
    #pragma unroll
    for (int m = 0; m < 4; m++) {
        int d = tid + NT * m;
        int src = (d ^ (d >> 1)) ^ ((d & 1) * 0x300);
        float4 t = st4[src];
        vrx[m] = t.x; vix[m] = t.y; vry[m] = t.z; viy[m] = t.w;
    }
    __syncthreads();                                     // B3: st4 free

    // ---- layer 2: bits 9,8 in-reg; bits 5..0 shfl/DPP ----
    {
        float2 g0 = s_l2[0];
        l2pair(g0, vrx[0], vix[0], vrx[2], vix[2]);
        l2pair(g0, vrx[1], vix[1], vrx[3], vix[3]);
        l2pair(g0, vry[0], viy[0], vry[2], viy[2]);
        l2pair(g0, vry[1], viy[1], vry[3], viy[3]);
        float2 g1 = s_l2[1];
        l2pair(g1, vrx[0], vix[0], vrx[1], vix[1]);
        l2pair(g1, vrx[2], vix[2], vrx[3], vix[3]);
        l2pair(g1, vry[0], viy[0], vry[1], viy[1]);
        l2pair(g1, vry[2], viy[2], vry[3], viy[3]);
    }
    gate4_l2<5>(s_l2[4], tid, vrx, vix); gate4_l2<5>(s_l2[4], tid, vry, viy);
    gate4_l2<4>(s_l2[5], tid, vrx, vix); gate4_l2<4>(s_l2[5], tid, vry, viy);
    gate4_l2<3>(s_l2[6], tid, vrx, vix); gate4_l2<3>(s_l2[6], tid, vry, viy);
    gate4_l2<2>(s_l2[7], tid, vrx, vix); gate4_l2<2>(s_l2[7], tid, vry, viy);
    gate4_l2<1>(s_l2[8], tid, vrx, vix); gate4_l2<1>(s_l2[8], tid, vry, viy);
    gate4_l2<0>(s_l2[9], tid, vrx, vix); gate4_l2<0>(s_l2[9], tid, vry, viy);
    #pragma unroll
    for (int m = 0; m < 4; m++)
        st4[tid + NT * m] = make_float4(vrx[m], vix[m], vry[m], viy[m]);
    __syncthreads();                                     // B4
    {   // l2 bits 7,6: 4x4 in place -> FINAL state image
        int base = lane | (wave << 8);
        float4 w00 = st4[base], w01 = st4[base | 64], w10 = st4[base | 128], w11 = st4[base | 192];
        float2 g2 = s_l2[2], g3 = s_l2[3];
        l2pair(g2, w00.x, w00.y, w10.x, w10.y);
        l2pair(g2, w00.z, w00.w, w10.z, w10.w);
        l2pair(g2, w01.x, w01.y, w11.x, w11.y);
        l2pair(g2, w01.z, w01.w, w11.z, w11.w);
        l2pair(g3, w00.x, w00.y, w01.x, w01.y);
        l2pair(g3, w00.z, w00.w, w01.z, w01.w);
        l2pair(g3, w10.x, w10.y, w11.x, w11.y);
        l2pair(g3, w10.z, w10.w, w11.z, w11.w);
        st4[base] = w00; st4[base | 64] = w01; st4[base | 128] = w10; st4[base | 192] = w11;
    }
    __syncthreads();                                     // B5: final state ready

    // ---- obs phase: wave owns obs wave*16..wave*16+15; 2 chunks x 2 passes ----
    const char* stb = (const char*)st4;
    float2* cbw = &cb[wave][lane * 9];
    const float2* cbr = &cb[wave][(lane >> 3) * (8 * 9) + (lane & 7)];
    float a0r[8], a0i[8], a1r[8], a1i[8];
    #pragma unroll 1
    for (int c = 0; c < 2; c++) {
        float2 pacc[8];
        // pass 0: a-side r in [0,8)
        #pragma unroll
        for (int j = 0; j < 8; j++) {
            float4 t = st4[(j << 6) | lane];
            a0r[j] = t.x; a0i[j] = t.y; a1r[j] = t.z; a1i[j] = t.w;
        }
        #pragma unroll 2
        for (int j = 0; j < 8; j++)
            pacc[j] = obs_one_p2<0>(s_meta[(wave << 4) + c * 8 + j], lane,
                                    a0r, a0i, a1r, a1i, stb);
        // pass 1: a-side r in [8,16)
        #pragma unroll
        for (int j = 0; j < 8; j++) {
            float4 t = st4[((8 + j) << 6) | lane];
            a0r[j] = t.x; a0i[j] = t.y; a1r[j] = t.z; a1i[j] = t.w;
        }
        #pragma unroll 2
        for (int j = 0; j < 8; j++) {
            float2 p = obs_one_p2<1>(s_meta[(wave << 4) + c * 8 + j], lane,
                                     a0r, a0i, a1r, a1i, stb);
            pacc[j].x += p.x; pacc[j].y += p.y;
        }
        #pragma unroll
        for (int j = 0; j < 8; j++) cbw[j] = pacc[j];
        // chunk drain: lane L sums lanes 8g..8g+7 (g=L>>3) for obs j=L&7,
        // then xor-combine the 8 groups (masks 8,16,32).
        float sx = 0.f, sy = 0.f;
        #pragma unroll
        for (int k = 0; k < 8; k++) {
            float2 v = cbr[k * 9];
            sx += v.x; sy += v.y;
        }
        sx += __shfl_xor(sx, 8, 64);  sy += __shfl_xor(sy, 8, 64);
        sx += __shfl_xor(sx, 16, 64); sy += __shfl_xor(sy, 16, 64);
        sx += __shfl_xor(sx, 32, 64); sy += __shfl_xor(sy, 32, 64);
        if (lane < 8) {
            const int oidx = (wave << 4) + c * 8 + lane;
            out[(size_t)row0 * HID + oidx] = sx;
            out[(size_t)row1 * HID + oidx] = sy;
        }
    }
}

extern "C" void kernel_launch(void* const* d_in, const int* in_sizes, int n_in,
                              void* d_out, int out_size, void* d_ws, size_t ws_size,
                              hipStream_t stream) {
    const float* x   = (const float*)d_in[0];
    const float* rx0 = (const float*)d_in[1];
    const float* ry0 = (const float*)d_in[2];
    const float* ry1 = (const float*)d_in[3];
    const int*   op  = (const int*)d_in[4];
    float* o = (float*)d_out;
    const int rows = in_sizes[0] / DIM;    // B*T = 2048
    qsa_kernel<<<rows / 2, NT, 0, stream>>>(x, rx0, ry0, ry1, op, o);
}

// Round 24
// 33.503 us; speedup vs baseline: 2.1017x; 2.1017x over previous
//
#include <hip/hip_runtime.h>
#include <math.h>

#define NQ 10
#define DIM 1024
#define HID 64
#define NT 256

template<int CTRL>
__device__ __forceinline__ float fdpp(float v) {
    return __int_as_float(__builtin_amdgcn_update_dpp(
        0, __float_as_int(v), CTRL, 0xF, 0xF, true));
}

// fused RY*RX 2x2 complex gate (validated r2..r21)
__device__ __forceinline__ void l1pair(float4 g, float& r0, float& i0, float& r1, float& i1) {
    float n0r = g.x * r0 - g.y * i0 - g.z * r1 + g.w * i1;
    float n0i = g.x * i0 + g.y * r0 - g.z * i1 - g.w * r1;
    float n1r = g.z * r0 + g.w * i0 + g.x * r1 + g.y * i1;
    float n1i = g.z * i0 - g.w * r0 + g.x * i1 - g.y * r1;
    r0 = n0r; i0 = n0i; r1 = n1r; i1 = n1i;
}
__device__ __forceinline__ void l2pair(float2 g, float& r0, float& i0, float& r1, float& i1) {
    float n0r = g.x * r0 - g.y * r1, n0i = g.x * i0 - g.y * i1;
    float n1r = g.y * r0 + g.x * r1, n1i = g.y * i0 + g.x * i1;
    r0 = n0r; i0 = n0i; r1 = n1r; i1 = n1i;
}

// cross-lane fetch of v from lane^(1<<P): DPP for P=0,1, shfl for P>=2
template<int P>
__device__ __forceinline__ float xl(float v) {
    if constexpr (P == 0)      return fdpp<0xB1>(v);   // lane^1
    else if constexpr (P == 1) return fdpp<0x4E>(v);   // lane^2
    else                       return __shfl_xor(v, 1 << P, 64);
}

template<int P>
__device__ __forceinline__ void gate4_l1(float4 g, int tid, float (&vr)[4], float (&vi)[4]) {
    const float fsb = ((tid >> P) & 1) ? 1.f : -1.f;
    const float Bs = fsb * g.y, Cs = fsb * g.z;
    #pragma unroll
    for (int m = 0; m < 4; m++) {
        float ur = xl<P>(vr[m]);
        float ui = xl<P>(vi[m]);
        float nr = g.x * vr[m] + Bs * vi[m] + Cs * ur + g.w * ui;
        float ni = g.x * vi[m] - Bs * vr[m] + Cs * ui - g.w * ur;
        vr[m] = nr; vi[m] = ni;
    }
}
template<int P>
__device__ __forceinline__ void gate4_l2(float2 g, int tid, float (&vr)[4], float (&vi)[4]) {
    const float fsb = ((tid >> P) & 1) ? 1.f : -1.f;
    const float ssf = fsb * g.y;
    #pragma unroll
    for (int m = 0; m < 4; m++) {
        float ur = xl<P>(vr[m]);
        float ui = xl<P>(vi[m]);
        vr[m] = g.x * vr[m] + ssf * ur;
        vi[m] = g.x * vi[m] + ssf * ui;
    }
}

// ---- obs partial sums (validated r6/r12/r14/r15/r16/r18/r20/r21) ----
template<int HB, int CM>
__device__ __forceinline__ float obs_halved(const float (&vr)[16], const float (&vi)[16],
                                            const char* stb, int base_cx, int w1) {
    float a0 = 0.f, a1 = 0.f;
    #pragma unroll
    for (int idx = 0; idx < 8; idx++) {
        const int lo = idx & ((1 << HB) - 1);
        const int r  = ((idx >> HB) << (HB + 1)) | lo;      // compile-time
        const float2 c = *(const float2*)(stb + (base_cx ^ (r << 9)));
        float t;
        if constexpr (CM) t = vr[r] * c.y - vi[r] * c.x;    // odd nY
        else              t = vr[r] * c.x + vi[r] * c.y;    // even nY
        const int cf = 0x40000000 | (((w1 >> r) & 1) << 31);
        if (idx & 1) a1 = fmaf(__int_as_float(cf), t, a1);
        else         a0 = fmaf(__int_as_float(cf), t, a0);
    }
    return a0 + a1;
}
template<int CM>
__device__ __forceinline__ float obs_full(const float (&vr)[16], const float (&vi)[16],
                                          const char* stb, int base_c, int w1) {
    float a0 = 0.f, a1 = 0.f;
    #pragma unroll
    for (int r = 0; r < 16; r++) {
        const float2 c = *(const float2*)(stb + base_c + (r << 9));
        float t;
        if constexpr (CM) t = vr[r] * c.y - vi[r] * c.x;
        else              t = vr[r] * c.x + vi[r] * c.y;
        const int cf = 0x3F800000 | (((w1 >> r) & 1) << 31);
        if (r & 1) a1 = fmaf(__int_as_float(cf), t, a1);
        else       a0 = fmaf(__int_as_float(cf), t, a0);
    }
    return a0 + a1;
}
__device__ __forceinline__ float obs_diag(const float (&vr)[16], const float (&vi)[16], int w1) {
    float a0 = 0.f, a1 = 0.f;
    #pragma unroll
    for (int r = 0; r < 16; r++) {
        float t = fmaf(vr[r], vr[r], vi[r] * vi[r]);
        const int cf = 0x3F800000 | (((w1 >> r) & 1) << 31);
        if (r & 1) a1 = fmaf(__int_as_float(cf), t, a1);
        else       a0 = fmaf(__int_as_float(cf), t, a0);
    }
    return a0 + a1;
}
__device__ __forceinline__ int4 make_meta(const int* op_codes, int o) {
    int xm = 0, yzm = 0, ny = 0;
    #pragma unroll
    for (int q = 0; q < NQ; q++) {
        int code = op_codes[o * NQ + q];
        int bit  = 1 << (NQ - 1 - q);       // qubit q = element bit 9-q
        if (code == 1) xm |= bit;
        else if (code == 2) { xm |= bit; yzm |= bit; ny++; }
        else if (code == 3) yzm |= bit;
    }
    const int cm = ny & 1, gflip = (ny >> 1) & 1;
    const int yh = yzm >> 6;
    int w1 = 0;
    #pragma unroll
    for (int r = 0; r < 16; r++)
        w1 |= ((__popc(r & yh) & 1) ^ gflip) << r;
    const int xmr = (xm >> 6) & 15;
    int hbc;
    if (xm == 0)      hbc = 5;              // diagonal
    else if (xmr)     hbc = __ffs(xmr) - 1; // halved on reg bit 0..3
    else              hbc = 4;              // lane-only xm: full 16
    return make_int4(xm, yzm & 63, w1, hbc | (cm << 3));
}
__device__ __forceinline__ float obs_one(int4 mt, int lane,
        const float (&vr)[16], const float (&vi)[16], const char* stb) {
    const int xm   = __builtin_amdgcn_readfirstlane(mt.x);
    const int yzml = __builtin_amdgcn_readfirstlane(mt.y);
    const int w1   = __builtin_amdgcn_readfirstlane(mt.z);
    const int knd  = __builtin_amdgcn_readfirstlane(mt.w);
    const int hbc = knd & 7, cm = knd >> 3;
    float p;
    if (hbc == 5) {
        p = obs_diag(vr, vi, w1);
    } else {
        const int xml = xm & 63, xmr = (xm >> 6) & 15;
        const int base_cx = (xmr << 9) | ((lane ^ xml) << 3);
        switch (hbc | (cm << 3)) {
            case 0:     p = obs_halved<0,0>(vr, vi, stb, base_cx, w1); break;
            case 1:     p = obs_halved<1,0>(vr, vi, stb, base_cx, w1); break;
            case 2:     p = obs_halved<2,0>(vr, vi, stb, base_cx, w1); break;
            case 3:     p = obs_halved<3,0>(vr, vi, stb, base_cx, w1); break;
            case 4:     p = obs_full<0>(vr, vi, stb, base_cx, w1);     break;
            case 8 | 0: p = obs_halved<0,1>(vr, vi, stb, base_cx, w1); break;
            case 8 | 1: p = obs_halved<1,1>(vr, vi, stb, base_cx, w1); break;
            case 8 | 2: p = obs_halved<2,1>(vr, vi, stb, base_cx, w1); break;
            case 8 | 3: p = obs_halved<3,1>(vr, vi, stb, base_cx, w1); break;
            default:    p = obs_full<1>(vr, vi, stb, base_cx, w1);     break;
        }
    }
    const int sl = __popc(lane & yzml) & 1;
    return __int_as_float(__float_as_int(p) ^ (sl << 31));
}

// FINAL: 1 row per 256-thread block (4 waves). r21 configuration — the best
// measured point of this structure (33.5 us, vs 63.3 us baseline). Session
// law: body needs ~90-100 VGPR; caps below that spill catastrophically
// (r17/r23); deeper ILP (2 rows) exceeds every usable launch-bounds tier.
__global__ __launch_bounds__(NT, 5) void qsa_kernel(
    const float* __restrict__ x,
    const float* __restrict__ rx0,
    const float* __restrict__ ry0,
    const float* __restrict__ ry1,
    const int*   __restrict__ op_codes,
    float* __restrict__ out)
{
    __shared__ float2 st[DIM];              // row state (8 KB)
    __shared__ float  cb[4][64 * 17];       // per-wave transpose-reduce buffer
    __shared__ float4 s_l1[NQ];
    __shared__ float2 s_l2[NQ];
    __shared__ int4   s_meta[HID];
    __shared__ float  wsum[4];

    const int tid  = threadIdx.x;
    const int lane = tid & 63;
    const int wave = tid >> 6;
    const int row  = blockIdx.x;            // 2048 blocks

    // ---- setup ----
    if (tid < NQ) {
        float a = 0.5f * rx0[tid], b = 0.5f * ry0[tid];
        float c1 = cosf(a), s1 = sinf(a), c2 = cosf(b), s2 = sinf(b);
        s_l1[tid] = make_float4(c1 * c2, s1 * s2, s2 * c1, c2 * s1);  // A,B,C,D
    } else if (tid < 2 * NQ) {
        float a = 0.5f * ry1[tid - NQ];
        s_l2[tid - NQ] = make_float2(cosf(a), sinf(a));
    }
    if (tid >= 64 && tid < 64 + HID)
        s_meta[tid - 64] = make_meta(op_codes, tid - 64);

    // ---- load 4 elems/thread + block normalize ----
    float vr[4], vi[4];
    float ssq = 0.f;
    const float* xr = x + (size_t)row * DIM;
    #pragma unroll
    for (int m = 0; m < 4; m++) {
        vr[m] = xr[tid + NT * m];
        vi[m] = 0.f;
        ssq += vr[m] * vr[m];
    }
    #pragma unroll
    for (int off = 32; off; off >>= 1) ssq += __shfl_xor(ssq, off, 64);
    if (lane == 0) wsum[wave] = ssq;
    __syncthreads();                                     // B0 (also fences tables)
    {
        float inv = 1.0f / sqrtf(wsum[0] + wsum[1] + wsum[2] + wsum[3]);
        #pragma unroll
        for (int m = 0; m < 4; m++) vr[m] *= inv;
    }

    // ---- layer 1: bits 9,8 in-reg; 7,6 LDS 4x4; 5..0 shuffle/DPP gates ----
    {
        float4 g0 = s_l1[0];
        l1pair(g0, vr[0], vi[0], vr[2], vi[2]);
        l1pair(g0, vr[1], vi[1], vr[3], vi[3]);
        float4 g1 = s_l1[1];
        l1pair(g1, vr[0], vi[0], vr[1], vi[1]);
        l1pair(g1, vr[2], vi[2], vr[3], vi[3]);
    }
    #pragma unroll
    for (int m = 0; m < 4; m++) st[tid + NT * m] = make_float2(vr[m], vi[m]);
    __syncthreads();                                     // B1
    {
        int base = lane | (wave << 8);
        float2 w00 = st[base], w01 = st[base | 64], w10 = st[base | 128], w11 = st[base | 192];
        float4 g2 = s_l1[2], g3 = s_l1[3];
        l1pair(g2, w00.x, w00.y, w10.x, w10.y);
        l1pair(g2, w01.x, w01.y, w11.x, w11.y);
        l1pair(g3, w00.x, w00.y, w01.x, w01.y);
        l1pair(g3, w10.x, w10.y, w11.x, w11.y);
        st[base] = w00; st[base | 64] = w01; st[base | 128] = w10; st[base | 192] = w11;
    }
    __syncthreads();                                     // B2
    #pragma unroll
    for (int m = 0; m < 4; m++) { float2 t = st[tid + NT * m]; vr[m] = t.x; vi[m] = t.y; }
    gate4_l1<5>(s_l1[4], tid, vr, vi);
    gate4_l1<4>(s_l1[5], tid, vr, vi);
    gate4_l1<3>(s_l1[6], tid, vr, vi);
    gate4_l1<2>(s_l1[7], tid, vr, vi);
    gate4_l1<1>(s_l1[8], tid, vr, vi);
    gate4_l1<0>(s_l1[9], tid, vr, vi);

    // ---- CNOT ring: composed permutation gather ----
    #pragma unroll
    for (int m = 0; m < 4; m++) st[tid + NT * m] = make_float2(vr[m], vi[m]);
    __syncthreads();                                     // B3
    #pragma unroll
    for (int m = 0; m < 4; m++) {
        int d = tid + NT * m;
        int src = (d ^ (d >> 1)) ^ ((d & 1) * 0x300);
        float2 t = st[src];
        vr[m] = t.x; vi[m] = t.y;
    }
    __syncthreads();                                     // B4

    // ---- layer 2 (RY) ----
    {
        float2 g0 = s_l2[0];
        l2pair(g0, vr[0], vi[0], vr[2], vi[2]);
        l2pair(g0, vr[1], vi[1], vr[3], vi[3]);
        float2 g1 = s_l2[1];
        l2pair(g1, vr[0], vi[0], vr[1], vi[1]);
        l2pair(g1, vr[2], vi[2], vr[3], vi[3]);
    }
    #pragma unroll
    for (int m = 0; m < 4; m++) st[tid + NT * m] = make_float2(vr[m], vi[m]);
    __syncthreads();                                     // B5
    {
        int base = lane | (wave << 8);
        float2 w00 = st[base], w01 = st[base | 64], w10 = st[base | 128], w11 = st[base | 192];
        float2 g2 = s_l2[2], g3 = s_l2[3];
        l2pair(g2, w00.x, w00.y, w10.x, w10.y);
        l2pair(g2, w01.x, w01.y, w11.x, w11.y);
        l2pair(g3, w00.x, w00.y, w01.x, w01.y);
        l2pair(g3, w10.x, w10.y, w11.x, w11.y);
        st[base] = w00; st[base | 64] = w01; st[base | 128] = w10; st[base | 192] = w11;
    }
    __syncthreads();                                     // B6
    #pragma unroll
    for (int m = 0; m < 4; m++) { float2 t = st[tid + NT * m]; vr[m] = t.x; vi[m] = t.y; }
    gate4_l2<5>(s_l2[4], tid, vr, vi);
    gate4_l2<4>(s_l2[5], tid, vr, vi);
    gate4_l2<3>(s_l2[6], tid, vr, vi);
    gate4_l2<2>(s_l2[7], tid, vr, vi);
    gate4_l2<1>(s_l2[8], tid, vr, vi);
    gate4_l2<0>(s_l2[9], tid, vr, vi);
    #pragma unroll
    for (int m = 0; m < 4; m++) st[tid + NT * m] = make_float2(vr[m], vi[m]);
    __syncthreads();                                     // B7: final state ready

    // ---- obs phase: wave owns obs wave*16..wave*16+15 (unroll 4 for MLP) ----
    float vra[16], via[16];                              // a-side fragment
    #pragma unroll
    for (int r = 0; r < 16; r++) {
        float2 t = st[(r << 6) | lane];
        vra[r] = t.x; via[r] = t.y;
    }
    const char* stb = (const char*)st;
    float* cbw = &cb[wave][lane * 17];
    const float* cbr = &cb[wave][(lane >> 4) * (16 * 17) + (lane & 15)];
    #pragma unroll 4
    for (int oo = 0; oo < 16; oo++)
        cbw[oo] = obs_one(s_meta[(wave << 4) + oo], lane, vra, via, stb);
    float s0 = 0.f, s1 = 0.f, s2 = 0.f, s3 = 0.f;
    #pragma unroll
    for (int k = 0; k < 16; k += 4) {
        s0 += cbr[(k + 0) * 17];
        s1 += cbr[(k + 1) * 17];
        s2 += cbr[(k + 2) * 17];
        s3 += cbr[(k + 3) * 17];
    }
    float tot = (s0 + s1) + (s2 + s3);                   // quarter-sum, obs lane&15
    tot += __shfl_xor(tot, 16, 64);
    tot += __shfl_xor(tot, 32, 64);                      // full 64-lane sum
    if (lane < 16)
        out[(size_t)row * HID + (wave << 4) + lane] = tot;
}

extern "C" void kernel_launch(void* const* d_in, const int* in_sizes, int n_in,
                              void* d_out, int out_size, void* d_ws, size_t ws_size,
                              hipStream_t stream) {
    const float* x   = (const float*)d_in[0];
    const float* rx0 = (const float*)d_in[1];
    const float* ry0 = (const float*)d_in[2];
    const float* ry1 = (const float*)d_in[3];
    const int*   op  = (const int*)d_in[4];
    float* o = (float*)d_out;
    const int rows = in_sizes[0] / DIM;    // B*T = 2048
    qsa_kernel<<<rows, NT, 0, stream>>>(x, rx0, ry0, ry1, op, o);
}